// Round 2
// baseline (351.568 us; speedup 1.0000x reference)
//
#include <hip/hip_runtime.h>
#include <hip/hip_cooperative_groups.h>

namespace cg = cooperative_groups;

// CriticGCN: out = D^-1/2 (A+I) D^-1/2 (x W1) + b1, then @ W_head + b_head.
// Head folded through the (linear) aggregation:
//   w = W1 @ W_head (100 floats), c = b1.W_head + b_head
//   s[i] = x[i].w ; dinv[i] = rsqrt(deg[i]+1)
//   out[d] = c + dinv[d]^2 s[d] + Sum_{e:s->d} dinv[s] dinv[d] s[s]
//
// R7: single cooperative dispatch. R5/R6 post-mortem showed ~5 us per
// dispatch slot dominates our ~16 us controllable slice (work deltas moved
// dur_us the WRONG way when dispatch count rose). So: R5's proven 3-kernel
// semantics become 3 phases of ONE hipLaunchCooperativeKernel with 2
// grid.sync()s (each ~1-3 us < ~4.5 us dispatch boundary).
//   Phase A: fold w,c (blocks 0..100) | zero deg (blocks 101..149)
//   Phase B: deg[dst]++ int4 | seed out=c float4 | grid-stride score waves
//   Phase C: edge scatter int2 (3 gathers + 2 rsqrt) | self term
// Fallback: if cooperative launch fails, enqueue the R5 3-kernel path
// (bit-identical math, known 102.8 us).

#define N_NODES 50000
#define F_IN    100
#define H_DIM   1024
#define N_EDGES 200000

// ---------------------------------------------------------------- cooperative
__global__ void __launch_bounds__(256)
k_fused(const float* __restrict__ x, const int* __restrict__ ei,
        const float* __restrict__ W1, const float* __restrict__ b1,
        const float* __restrict__ Wh, const float* __restrict__ bh,
        float* __restrict__ w, float* __restrict__ c,
        unsigned* __restrict__ deg, float* __restrict__ sbuf,
        float* __restrict__ out)
{
    const cg::grid_group grid = cg::this_grid();
    const int b   = blockIdx.x;
    const int t   = threadIdx.x;
    const int tid = b * 256 + t;

    // ---- Phase A: fold w = W1@Wh, c = b1.Wh + bh | zero deg ----
    if (b <= 100) {
        const float* row = (b < 100) ? (W1 + (size_t)b * H_DIM) : b1;
        float s = 0.0f;
        #pragma unroll
        for (int k = 0; k < H_DIM / 256; ++k) {
            const int h = t + 256 * k;
            s += row[h] * Wh[h];
        }
        #pragma unroll
        for (int off = 32; off > 0; off >>= 1) s += __shfl_down(s, off, 64);
        __shared__ float red[4];
        const int wave = t >> 6, lane = t & 63;
        if (lane == 0) red[wave] = s;
        __syncthreads();
        if (t == 0) {
            const float tot = red[0] + red[1] + red[2] + red[3];
            if (b < 100) w[b] = tot;
            else         *c  = tot + bh[0];
        }
    } else if (b <= 149) {
        const int g = (b - 101) * 256 + t;               // 12500 float4
        if (g < N_NODES / 4)
            ((float4*)deg)[g] = make_float4(0.f, 0.f, 0.f, 0.f);
    }

    grid.sync();

    // ---- Phase B: deg count | seed out=c | wave-per-node score ----
    if (tid < N_EDGES / 4) {                             // 50000 threads
        const int4 d4 = ((const int4*)(ei + N_EDGES))[tid];
        atomicAdd(&deg[d4.x], 1u);
        atomicAdd(&deg[d4.y], 1u);
        atomicAdd(&deg[d4.z], 1u);
        atomicAdd(&deg[d4.w], 1u);
    } else if (tid < N_EDGES / 4 + N_NODES / 4) {        // 12500 threads
        const float cv = c[0];
        ((float4*)out)[tid - N_EDGES / 4] = make_float4(cv, cv, cv, cv);
    }
    {
        const int nwaves = (gridDim.x << 8) >> 6;        // blocks*256/64
        const int gw0    = tid >> 6;
        const int lane   = tid & 63;
        const float wl  = w[lane];
        const float wh2 = (lane < F_IN - 64) ? w[64 + lane] : 0.0f;
        for (int n = gw0; n < N_NODES; n += nwaves) {
            const float* row = x + (size_t)n * F_IN;
            float s = row[lane] * wl;
            if (lane < F_IN - 64) s += row[64 + lane] * wh2;
            #pragma unroll
            for (int off = 32; off > 0; off >>= 1) s += __shfl_down(s, off, 64);
            if (lane == 0) sbuf[n] = s;
        }
    }

    grid.sync();

    // ---- Phase C: edge scatter | self term ----
    if (tid < N_EDGES / 2) {                             // 100000 threads, int2
        const int2 s2 = ((const int2*)ei)[tid];
        const int2 d2 = ((const int2*)(ei + N_EDGES))[tid];
        const float u0 = sbuf[s2.x] * rsqrtf((float)deg[s2.x] + 1.0f)
                                    * rsqrtf((float)deg[d2.x] + 1.0f);
        const float u1 = sbuf[s2.y] * rsqrtf((float)deg[s2.y] + 1.0f)
                                    * rsqrtf((float)deg[d2.y] + 1.0f);
        unsafeAtomicAdd(&out[d2.x], u0);
        unsafeAtomicAdd(&out[d2.y], u1);
    } else if (tid < N_EDGES / 2 + N_NODES) {            // 50000 threads
        const int i = tid - N_EDGES / 2;
        const float dv = rsqrtf((float)deg[i] + 1.0f);
        unsafeAtomicAdd(&out[i], dv * dv * sbuf[i]);
    }
}

// ---------------------------------------------------------------- R5 fallback
__global__ void __launch_bounds__(256)
k0_fold_zero(const float* __restrict__ W1, const float* __restrict__ b1,
             const float* __restrict__ Wh, const float* __restrict__ bh,
             float* __restrict__ w, float* __restrict__ c,
             float4* __restrict__ deg_zero)
{
    const int b = blockIdx.x;
    const int t = threadIdx.x;
    if (b <= 100) {
        const float* row = (b < 100) ? (W1 + (size_t)b * H_DIM) : b1;
        float s = 0.0f;
        #pragma unroll
        for (int k = 0; k < H_DIM / 256; ++k) {
            const int h = t + 256 * k;
            s += row[h] * Wh[h];
        }
        #pragma unroll
        for (int off = 32; off > 0; off >>= 1) s += __shfl_down(s, off, 64);
        __shared__ float red[4];
        const int wave = t >> 6, lane = t & 63;
        if (lane == 0) red[wave] = s;
        __syncthreads();
        if (t == 0) {
            const float tot = red[0] + red[1] + red[2] + red[3];
            if (b < 100) w[b] = tot;
            else         *c  = tot + bh[0];
        }
    } else {
        const int g = (b - 101) * 256 + t;
        if (g < N_NODES / 4)
            deg_zero[g] = make_float4(0.f, 0.f, 0.f, 0.f);
    }
}

__global__ void __launch_bounds__(256)
k1_deg_seed_score(const float* __restrict__ x, const int* __restrict__ ei,
                  const float* __restrict__ w, const float* __restrict__ c,
                  unsigned* __restrict__ deg, float* __restrict__ sbuf,
                  float4* __restrict__ out4)
{
    const int tid   = blockIdx.x * 256 + threadIdx.x;
    const int gwave = tid >> 6;
    const int lane  = tid & 63;

    if (tid < N_EDGES / 4) {
        const int4 d4 = ((const int4*)(ei + N_EDGES))[tid];
        atomicAdd(&deg[d4.x], 1u);
        atomicAdd(&deg[d4.y], 1u);
        atomicAdd(&deg[d4.z], 1u);
        atomicAdd(&deg[d4.w], 1u);
    } else if (tid < N_EDGES / 4 + N_NODES / 4) {
        const float cv = c[0];
        out4[tid - N_EDGES / 4] = make_float4(cv, cv, cv, cv);
    }

    if (gwave < N_NODES) {
        const float* row = x + (size_t)gwave * F_IN;
        float s = row[lane] * w[lane];
        if (lane < F_IN - 64) s += row[64 + lane] * w[64 + lane];
        #pragma unroll
        for (int off = 32; off > 0; off >>= 1) s += __shfl_down(s, off, 64);
        if (lane == 0) sbuf[gwave] = s;
    }
}

__global__ void __launch_bounds__(256)
k2_scatter(const int* __restrict__ ei, const unsigned* __restrict__ deg,
           const float* __restrict__ sbuf, float* __restrict__ out)
{
    const int tid = blockIdx.x * 256 + threadIdx.x;
    if (tid < N_EDGES / 2) {
        const int2 s2 = ((const int2*)ei)[tid];
        const int2 d2 = ((const int2*)(ei + N_EDGES))[tid];
        const float u0 = sbuf[s2.x] * rsqrtf((float)deg[s2.x] + 1.0f)
                                    * rsqrtf((float)deg[d2.x] + 1.0f);
        const float u1 = sbuf[s2.y] * rsqrtf((float)deg[s2.y] + 1.0f)
                                    * rsqrtf((float)deg[d2.y] + 1.0f);
        unsafeAtomicAdd(&out[d2.x], u0);
        unsafeAtomicAdd(&out[d2.y], u1);
    } else if (tid < N_EDGES / 2 + N_NODES) {
        const int i = tid - N_EDGES / 2;
        const float dv = rsqrtf((float)deg[i] + 1.0f);
        unsafeAtomicAdd(&out[i], dv * dv * sbuf[i]);
    }
}

// ---------------------------------------------------------------- launch
extern "C" void kernel_launch(void* const* d_in, const int* in_sizes, int n_in,
                              void* d_out, int out_size, void* d_ws, size_t ws_size,
                              hipStream_t stream)
{
    const float* x   = (const float*)d_in[0];   // (50000,100)
    const int*   ei  = (const int*)  d_in[1];   // (2,200000)
    const float* W1  = (const float*)d_in[2];   // (100,1024)
    const float* b1  = (const float*)d_in[3];   // (1024,)
    const float* Wh  = (const float*)d_in[4];   // (1024,)
    const float* bh  = (const float*)d_in[5];   // (1,)
    float*       out = (float*)d_out;           // (50000,)

    // ws layout (4B units): w[100] c[1] pad->128 | deg[50000] | s[50000]
    float*    ws_f = (float*)d_ws;
    float*    w    = ws_f;
    float*    c    = ws_f + 100;
    unsigned* deg  = (unsigned*)(ws_f + 128);
    float*    sbuf = ws_f + 128 + N_NODES;

    // Grid: residency-safe for cooperative launch. 1024 blocks (4/CU) gives
    // 4096 score waves (~12 nodes each) and covers phase C's 150000 threads
    // one-shot. Clamp by the occupancy query (cached; pure query, capture-ok).
    static int gblocks = 0;
    if (gblocks == 0) {
        int occ = 0;
        if (hipOccupancyMaxActiveBlocksPerMultiprocessor(&occ, k_fused, 256, 0)
                == hipSuccess && occ > 0)
            gblocks = occ * 256;                 // 256 CUs
        else
            gblocks = 1024;
        if (gblocks > 1024) gblocks = 1024;
        if (gblocks < 640)  gblocks = 640;       // >=150000/256 for phase C
    }

    void* args[] = {(void*)&x, (void*)&ei, (void*)&W1, (void*)&b1,
                    (void*)&Wh, (void*)&bh, (void*)&w, (void*)&c,
                    (void*)&deg, (void*)&sbuf, (void*)&out};
    hipError_t e = hipLaunchCooperativeKernel(k_fused, dim3(gblocks), dim3(256),
                                              args, 0, stream);
    if (e != hipSuccess) {
        // R5 fallback: 3 plain dispatches, identical math.
        k0_fold_zero<<<101 + (N_NODES / 4 + 255) / 256, 256, 0, stream>>>(
            W1, b1, Wh, bh, w, c, (float4*)deg);
        k1_deg_seed_score<<<(N_NODES * 64 + 255) / 256, 256, 0, stream>>>(
            x, ei, w, c, deg, sbuf, (float4*)out);
        k2_scatter<<<(N_EDGES / 2 + N_NODES + 255) / 256, 256, 0, stream>>>(
            ei, deg, sbuf, out);
    }
}

// Round 3
// 103.370 us; speedup vs baseline: 3.4011x; 3.4011x over previous
//
#include <hip/hip_runtime.h>

// CriticGCN: out = D^-1/2 (A+I) D^-1/2 (x W1) + b1, then @ W_head + b_head.
// Head folded through the (linear) aggregation:
//   w = W1 @ W_head (100 floats), c = b1.W_head + b_head
//   s[i] = x[i].w ; dinv[i] = rsqrt(deg[i]+1)
//   out[d] = c + dinv[d]^2 s[d] + Sum_{e:s->d} dinv[s] dinv[d] s[s]
//
// R8: REVERT to the verified R5 3-dispatch structure (102.8 us).
// Session evidence:
//   R6 (4 dispatches, leaner work): 107.3  -> +1 dispatch = +4.5 us; work
//       content inside kernels is timing-irrelevant (latency-bound).
//   R7 (1 cooperative dispatch): 351.6 -> grid.sync() ~130 us each on gfx950
//       (single-cacheline cross-XCD atomic barrier). Kernel boundaries ARE
//       the cheap grid sync on this chip.
// Dependency chains (zero->count->read-deg) x (fold->score->scatter) force
// exactly 3 boundaries without persistent state. dur = ~87 us harness poison
// fills (268 MB @ 76-78% HBM peak, fixed) + ~16 us for this chain.
//
//   K0: fold w = W1@Wh, c = b1.Wh + bh   (101 blocks) | zero deg (49 blocks)
//   K1: deg[dst]++ (int4, 50k threads) | seed out=c (float4) | score waves
//   K2: out[dst] += s[src]*dinv[src]*dinv[dst] per edge | out[i] += dinv^2 s[i]

#define N_NODES 50000
#define F_IN    100
#define H_DIM   1024
#define N_EDGES 200000

__global__ void __launch_bounds__(256)
k0_fold_zero(const float* __restrict__ W1, const float* __restrict__ b1,
             const float* __restrict__ Wh, const float* __restrict__ bh,
             float* __restrict__ w, float* __restrict__ c,
             float4* __restrict__ deg_zero)
{
    const int b = blockIdx.x;
    const int t = threadIdx.x;
    if (b <= 100) {
        const float* row = (b < 100) ? (W1 + (size_t)b * H_DIM) : b1;
        float s = 0.0f;
        #pragma unroll
        for (int k = 0; k < H_DIM / 256; ++k) {
            const int h = t + 256 * k;
            s += row[h] * Wh[h];
        }
        #pragma unroll
        for (int off = 32; off > 0; off >>= 1) s += __shfl_down(s, off, 64);
        __shared__ float red[4];
        const int wave = t >> 6, lane = t & 63;
        if (lane == 0) red[wave] = s;
        __syncthreads();
        if (t == 0) {
            const float tot = red[0] + red[1] + red[2] + red[3];
            if (b < 100) w[b] = tot;
            else         *c  = tot + bh[0];
        }
    } else {
        const int g = (b - 101) * 256 + t;           // 12500 float4 = deg[50000]
        if (g < N_NODES / 4)
            deg_zero[g] = make_float4(0.f, 0.f, 0.f, 0.f);
    }
}

// K1 — three independent jobs in one dispatch (12500 blocks):
//   tid < 50000            : deg[dst]++, 4 edges/thread via int4
//   tid in [50000, 62500)  : out[i..i+3] = c (float4 seed)
//   every wave (gwave<50k) : s[i] = x[i].w  (wave per node, coalesced rows)
__global__ void __launch_bounds__(256)
k1_deg_seed_score(const float* __restrict__ x, const int* __restrict__ ei,
                  const float* __restrict__ w, const float* __restrict__ c,
                  unsigned* __restrict__ deg, float* __restrict__ sbuf,
                  float4* __restrict__ out4)
{
    const int tid   = blockIdx.x * 256 + threadIdx.x;
    const int gwave = tid >> 6;
    const int lane  = tid & 63;

    if (tid < N_EDGES / 4) {                          // 50000 threads
        const int4 d4 = ((const int4*)(ei + N_EDGES))[tid];
        atomicAdd(&deg[d4.x], 1u);
        atomicAdd(&deg[d4.y], 1u);
        atomicAdd(&deg[d4.z], 1u);
        atomicAdd(&deg[d4.w], 1u);
    } else if (tid < N_EDGES / 4 + N_NODES / 4) {     // 12500 threads
        const float cv = c[0];
        out4[tid - N_EDGES / 4] = make_float4(cv, cv, cv, cv);
    }

    if (gwave < N_NODES) {
        const float* row = x + (size_t)gwave * F_IN;
        float s = row[lane] * w[lane];                              // 0..63
        if (lane < F_IN - 64) s += row[64 + lane] * w[64 + lane];   // 64..99
        #pragma unroll
        for (int off = 32; off > 0; off >>= 1) s += __shfl_down(s, off, 64);
        if (lane == 0) sbuf[gwave] = s;
    }
}

// K2 — scatter directly into out (seeded with c by K1):
//   tid < 100000           : 2 edges via int2: out[dst] += s[src]*dinv[src]*dinv[dst]
//   tid in [100000,150000) : self term out[i] += dinv[i]^2 * s[i]
__global__ void __launch_bounds__(256)
k2_scatter(const int* __restrict__ ei, const unsigned* __restrict__ deg,
           const float* __restrict__ sbuf, float* __restrict__ out)
{
    const int tid = blockIdx.x * 256 + threadIdx.x;
    if (tid < N_EDGES / 2) {
        const int2 s2 = ((const int2*)ei)[tid];
        const int2 d2 = ((const int2*)(ei + N_EDGES))[tid];
        const float u0 = sbuf[s2.x] * rsqrtf((float)deg[s2.x] + 1.0f)
                                    * rsqrtf((float)deg[d2.x] + 1.0f);
        const float u1 = sbuf[s2.y] * rsqrtf((float)deg[s2.y] + 1.0f)
                                    * rsqrtf((float)deg[d2.y] + 1.0f);
        unsafeAtomicAdd(&out[d2.x], u0);
        unsafeAtomicAdd(&out[d2.y], u1);
    } else if (tid < N_EDGES / 2 + N_NODES) {
        const int i = tid - N_EDGES / 2;
        const float dv = rsqrtf((float)deg[i] + 1.0f);
        unsafeAtomicAdd(&out[i], dv * dv * sbuf[i]);
    }
}

extern "C" void kernel_launch(void* const* d_in, const int* in_sizes, int n_in,
                              void* d_out, int out_size, void* d_ws, size_t ws_size,
                              hipStream_t stream)
{
    const float* x   = (const float*)d_in[0];   // (50000,100)
    const int*   ei  = (const int*)  d_in[1];   // (2,200000)
    const float* W1  = (const float*)d_in[2];   // (100,1024)
    const float* b1  = (const float*)d_in[3];   // (1024,)
    const float* Wh  = (const float*)d_in[4];   // (1024,)
    const float* bh  = (const float*)d_in[5];   // (1,)
    float*       out = (float*)d_out;           // (50000,)

    // ws layout (4B units): w[100] c[1] pad->128 | deg[50000] | s[50000]
    float*    ws_f = (float*)d_ws;
    float*    w    = ws_f;
    float*    c    = ws_f + 100;
    unsigned* deg  = (unsigned*)(ws_f + 128);
    float*    sbuf = ws_f + 128 + N_NODES;

    // K0: fold w,c (101 blocks) + zero deg (49 blocks)
    k0_fold_zero<<<101 + (N_NODES / 4 + 255) / 256, 256, 0, stream>>>(
        W1, b1, Wh, bh, w, c, (float4*)deg);
    // K1: deg count + seed out=c + wave-per-node score
    k1_deg_seed_score<<<(N_NODES * 64 + 255) / 256, 256, 0, stream>>>(
        x, ei, w, c, deg, sbuf, (float4*)out);
    // K2: normalized edge scatter + self term, directly into out
    k2_scatter<<<(N_EDGES / 2 + N_NODES + 255) / 256, 256, 0, stream>>>(
        ei, deg, sbuf, out);
}